// Round 3
// baseline (30.367 us; speedup 1.0000x reference)
//
#include <hip/hip_runtime.h>

// GCNCountry: out = ((leaky(leaky(adj@(x@Wgc)+bgc) @ W1 + b1) * dropmask) @ W2 + b2)[0]
// -> depends ONLY on row 0 of every intermediate. Vector chain:
//    v  = adj[0,:] @ x            (16 MB x-read -- the only big kernel, K1)
//    h0 = v @ Wgc                 (2 MB)   \
//    h1 = leaky(h0+bgc) @ W1      (2 MB)    } fused into ONE kernel with 2 internal
//    out = dropout(leaky(h1+b1)).W2 + b2   /  spin grid-barriers (128 co-resident blocks)
// 2 graph nodes total (was 4): node overhead ~3us each dominated the 17.5us.
//
// Barrier counters live in ws and are ZEROED BY K1 every call (kernel boundary
// guarantees visibility), so the captured graph is replay-deterministic and
// immune to the 0xAA ws-poison before the first timed replay.

constexpr int N_FEAT  = 512;
constexpr int N_HID1  = 1024;
constexpr int N_HID2  = 512;
constexpr float SLOPE  = 0.01f;
constexpr float DROP_P = 0.3f;

constexpr int VP_N = 32;    // v partials      [32][512]
constexpr int H1_N = 64;    // h1 partials     [64][512]
constexpr int VP_OFF  = 0;
constexpr int H0_OFF  = 16384;   // h0 partials [32][1024]
constexpr int H1_OFF  = 49152;
constexpr int CNT_OFF = 81920;   // 2 ints (cnt[0], cnt[16]) zeroed by K1

constexpr int NBLK = 128;        // fused-kernel grid; 128 blocks x 4 waves << 256 CUs -> co-resident

__device__ __forceinline__ float leaky(float x) { return x >= 0.f ? x : SLOPE * x; }

// ---------------- K1: v_part[rb][c] = sum_{rows in chunk rb} adj0[row] * x[row][c] ----------------
// grid (8 col-stripes of 64, 32 row-chunks of 256), 256 thr; float4 fully-coalesced x reads.
__global__ __launch_bounds__(256) void k1_adjrow_x(const float* __restrict__ x,
                                                   const float* __restrict__ adj0,
                                                   float* __restrict__ vp,
                                                   int* __restrict__ cnt) {
    const int tid = threadIdx.x;
    // zero the fused kernel's barrier counters (visible at kernel boundary)
    if (blockIdx.x == 0 && blockIdx.y == 0 && tid < 2) cnt[tid * 16] = 0;

    const int f4  = tid & 15;
    const int r   = tid >> 4;          // 0..15
    const int c0  = blockIdx.x * 64;   // col stripe
    const int rb  = blockIdx.y;        // row chunk
    const float4* x4 = reinterpret_cast<const float4*>(x);

    float4 acc = {0.f, 0.f, 0.f, 0.f};
    int row = rb * 256 + r;
    #pragma unroll
    for (int it = 0; it < 16; ++it, row += 16) {
        const float  a  = adj0[row];
        const float4 xv = x4[row * (N_FEAT / 4) + (c0 >> 2) + f4];
        acc.x = fmaf(a, xv.x, acc.x);
        acc.y = fmaf(a, xv.y, acc.y);
        acc.z = fmaf(a, xv.z, acc.z);
        acc.w = fmaf(a, xv.w, acc.w);
    }

    __shared__ float4 sm[256];
    sm[tid] = acc;
    __syncthreads();
    #pragma unroll
    for (int off = 128; off >= 16; off >>= 1) {
        if (tid < off) {
            float4 o = sm[tid + off];
            sm[tid].x += o.x; sm[tid].y += o.y; sm[tid].z += o.z; sm[tid].w += o.w;
        }
        __syncthreads();
    }
    if (tid < 16)
        reinterpret_cast<float4*>(vp + rb * N_FEAT + c0)[tid] = sm[tid];
}

// ---------------- fused: h0 -> (bar) -> h1 -> (bar) -> finalize ----------------
__device__ __forceinline__ void grid_barrier(int* cnt, int nblk) {
    __syncthreads();
    if (threadIdx.x == 0) {
        __threadfence();  // release my phase's stores (device scope)
        __hip_atomic_fetch_add(cnt, 1, __ATOMIC_RELEASE, __HIP_MEMORY_SCOPE_AGENT);
        while (__hip_atomic_load(cnt, __ATOMIC_ACQUIRE, __HIP_MEMORY_SCOPE_AGENT) < nblk)
            __builtin_amdgcn_s_sleep(1);
        __threadfence();  // acquire: invalidate stale L1/L2 before reading others' stores
    }
    __syncthreads();
}

__global__ __launch_bounds__(256, 1) void k_fused(const float* __restrict__ vp,
                                                  const float* __restrict__ Wgc,
                                                  const float* __restrict__ bgc,
                                                  const float* __restrict__ W1,
                                                  const float* __restrict__ b1,
                                                  const float* __restrict__ W2,
                                                  const float* __restrict__ b2,
                                                  const float* __restrict__ du0,
                                                  float* __restrict__ h0p,
                                                  float* __restrict__ h1p,
                                                  int* __restrict__ cnt,
                                                  float* __restrict__ out) {
    const int t   = threadIdx.x;
    const int bid = blockIdx.x;
    __shared__ float red[16][17];
    __shared__ float vl[16];

    // ---- Phase B: h0_part[kc][j] = sum_{k in chunk kc} v[k] * Wgc[k][j] ----
    // 128 blocks = 4 j-blocks x 32 k-chunks of 16; v reduced from 32 partials on the fly.
    {
        const int jb = bid & 3;
        const int kc = bid >> 2;
        const int k0 = kc * 16;
        const int kl = t & 15, pg = t >> 4;   // 16 partial-groups x 16 k
        red[pg][kl] = vp[(2 * pg) * N_FEAT + k0 + kl] + vp[(2 * pg + 1) * N_FEAT + k0 + kl];
        __syncthreads();
        if (t < 16) {
            float s = 0.f;
            #pragma unroll
            for (int p = 0; p < 16; ++p) s += red[p][t];
            vl[t] = s;
        }
        __syncthreads();
        const int j = jb * 256 + t;
        float acc = 0.f;
        #pragma unroll
        for (int k = 0; k < 16; ++k)
            acc = fmaf(vl[k], Wgc[(k0 + k) * N_HID1 + j], acc);
        h0p[kc * N_HID1 + j] = acc;
    }
    grid_barrier(&cnt[0], NBLK);

    // ---- Phase C: h1_part[kc][j] = sum_{k in chunk} leaky(h0[k]+bgc[k]) * W1[k][j] ----
    // 128 blocks = 2 j-blocks x 64 k-chunks of 16; h0 reduced from 32 partials on the fly.
    {
        const int jb = bid & 1;
        const int kc = bid >> 1;
        const int k0 = kc * 16;
        const int kl = t & 15, pg = t >> 4;
        red[pg][kl] = h0p[(2 * pg) * N_HID1 + k0 + kl] + h0p[(2 * pg + 1) * N_HID1 + k0 + kl];
        __syncthreads();
        if (t < 16) {
            float s = bgc[k0 + t];
            #pragma unroll
            for (int p = 0; p < 16; ++p) s += red[p][t];
            vl[t] = leaky(s);
        }
        __syncthreads();
        const int j = jb * 256 + t;
        float acc = 0.f;
        #pragma unroll
        for (int k = 0; k < 16; ++k)
            acc = fmaf(vl[k], W1[(k0 + k) * N_HID2 + j], acc);
        h1p[kc * N_HID2 + j] = acc;
    }

    // ---- barrier 2: everyone arrives; only block 0 spins and finalizes ----
    __syncthreads();
    if (t == 0) {
        __threadfence();
        __hip_atomic_fetch_add(&cnt[16], 1, __ATOMIC_RELEASE, __HIP_MEMORY_SCOPE_AGENT);
    }
    if (bid != 0) return;
    if (t == 0) {
        while (__hip_atomic_load(&cnt[16], __ATOMIC_ACQUIRE, __HIP_MEMORY_SCOPE_AGENT) < NBLK)
            __builtin_amdgcn_s_sleep(1);
        __threadfence();
    }
    __syncthreads();

    // ---- Phase D: reduce h1 partials, bias+leaky+dropout, dot W2[:,0], +b2 ----
    {
        float term = 0.f;
        #pragma unroll
        for (int rep = 0; rep < 2; ++rep) {
            const int j = rep * 256 + t;
            float s = b1[j];
            #pragma unroll
            for (int p = 0; p < H1_N; ++p) s += h1p[p * N_HID2 + j];
            float h = leaky(s);
            h = (du0[j] >= DROP_P) ? h / (1.0f - DROP_P) : 0.f;
            term = fmaf(h, W2[j], term);
        }
        #pragma unroll
        for (int off = 32; off; off >>= 1) term += __shfl_down(term, off, 64);
        __shared__ float red3[4];
        if ((t & 63) == 0) red3[t >> 6] = term;
        __syncthreads();
        if (t == 0) {
            float s = 0.f;
            #pragma unroll
            for (int w = 0; w < 4; ++w) s += red3[w];
            out[0] = s + b2[0];
        }
    }
}

extern "C" void kernel_launch(void* const* d_in, const int* in_sizes, int n_in,
                              void* d_out, int out_size, void* d_ws, size_t ws_size,
                              hipStream_t stream) {
    const float* x   = (const float*)d_in[0];
    const float* adj = (const float*)d_in[1];  // row 0 = first 8192 floats
    const float* Wgc = (const float*)d_in[2];
    const float* bgc = (const float*)d_in[3];
    const float* W1  = (const float*)d_in[4];
    const float* b1  = (const float*)d_in[5];
    const float* W2  = (const float*)d_in[6];
    const float* b2  = (const float*)d_in[7];
    const float* du  = (const float*)d_in[8];  // row 0 = first 512 floats
    float* out = (float*)d_out;
    float* ws  = (float*)d_ws;

    float* vp  = ws + VP_OFF;
    float* h0p = ws + H0_OFF;
    float* h1p = ws + H1_OFF;
    int*   cnt = (int*)(ws + CNT_OFF);

    k1_adjrow_x<<<dim3(8, 32), 256, 0, stream>>>(x, adj, vp, cnt);
    k_fused    <<<dim3(NBLK),  256, 0, stream>>>(vp, Wgc, bgc, W1, b1, W2, b2, du,
                                                 h0p, h1p, cnt, out);
}

// Round 4
// 25.820 us; speedup vs baseline: 1.1761x; 1.1761x over previous
//
#include <hip/hip_runtime.h>

// GCNCountry: out = ((leaky(leaky(adj@(x@Wgc)+bgc) @ W1 + b1) * dropmask) @ W2 + b2)[0]
// -> depends ONLY on row 0 of every intermediate. Vector chain:
//    v  = adj[0,:] @ x            (16 MB x-read, K1, 256 blocks -> 32 partials)
//    h0 = v @ Wgc                 (2 MB, K2, 16 blocks, FULL h0 out)
//    h1 = leaky(h0+bgc) @ W1      (2 MB, K3, 16 blocks, each h1[j] complete in one block)
//    out = dropout(leaky(h1+b1)).W2 + b2   (fused into K3 via last-arrive trick)
//
// Round-3 lesson: full spin grid-barriers cost ~10us each (128 agent-scope
// fences + cross-XCD spin). Kernel boundaries (~3us) are cheaper for all-to-all
// deps. K3's finalize needs only ONE block past the dep -> last-arrive pattern:
// 16 release fences, no spinning, deterministic (fixed summation order).

constexpr int N_FEAT  = 512;
constexpr int N_HID1  = 1024;
constexpr int N_HID2  = 512;
constexpr float SLOPE  = 0.01f;
constexpr float DROP_P = 0.3f;

constexpr int VP_N   = 32;      // v partials [32][512]
constexpr int VP_OFF = 0;
constexpr int H0_OFF = 16384;   // h0 [1024] (complete)
constexpr int PD_OFF = 17408;   // pd [16] per-block partial dots
constexpr int CNT_OFF = 17424;  // 1 int, zeroed by K1

constexpr int K2_BLK = 16;      // 64 j each
constexpr int K3_BLK = 16;      // 32 j each

__device__ __forceinline__ float leaky(float x) { return x >= 0.f ? x : SLOPE * x; }

// ---------------- K1: v_part[rb][c] = sum_{rows in chunk rb} adj0[row] * x[row][c] ----------------
// grid (8 col-stripes of 64, 32 row-chunks of 256), 256 thr; float4 fully-coalesced x reads.
__global__ __launch_bounds__(256) void k1_adjrow_x(const float* __restrict__ x,
                                                   const float* __restrict__ adj0,
                                                   float* __restrict__ vp,
                                                   int* __restrict__ cnt) {
    const int tid = threadIdx.x;
    if (blockIdx.x == 0 && blockIdx.y == 0 && tid == 0) cnt[0] = 0;  // visible at kernel boundary

    const int f4  = tid & 15;
    const int r   = tid >> 4;          // 0..15
    const int c0  = blockIdx.x * 64;   // col stripe
    const int rb  = blockIdx.y;        // row chunk
    const float4* x4 = reinterpret_cast<const float4*>(x);

    float4 acc = {0.f, 0.f, 0.f, 0.f};
    int row = rb * 256 + r;
    #pragma unroll
    for (int it = 0; it < 16; ++it, row += 16) {
        const float  a  = adj0[row];
        const float4 xv = x4[row * (N_FEAT / 4) + (c0 >> 2) + f4];
        acc.x = fmaf(a, xv.x, acc.x);
        acc.y = fmaf(a, xv.y, acc.y);
        acc.z = fmaf(a, xv.z, acc.z);
        acc.w = fmaf(a, xv.w, acc.w);
    }

    __shared__ float4 sm[256];
    sm[tid] = acc;
    __syncthreads();
    #pragma unroll
    for (int off = 128; off >= 16; off >>= 1) {
        if (tid < off) {
            float4 o = sm[tid + off];
            sm[tid].x += o.x; sm[tid].y += o.y; sm[tid].z += o.z; sm[tid].w += o.w;
        }
        __syncthreads();
    }
    if (tid < 16)
        reinterpret_cast<float4*>(vp + rb * N_FEAT + c0)[tid] = sm[tid];
}

// ---------------- K2: h0[j] = sum_{k<512} v[k] * Wgc[k][j]  (complete h0) ----------------
// 16 blocks x 64 j; thread (jl=t&63, kq=t>>6): 4 k-quarters of 128; v reduced in LDS first.
__global__ __launch_bounds__(256) void k2_v_wgc(const float* __restrict__ vp,
                                                const float* __restrict__ Wgc,
                                                float* __restrict__ h0) {
    const int t = threadIdx.x;
    __shared__ float vl[N_FEAT];
    __shared__ float sm[4][64];

    for (int idx = t; idx < N_FEAT; idx += 256) {
        float s = 0.f;
        #pragma unroll 4
        for (int p = 0; p < VP_N; ++p) s += vp[p * N_FEAT + idx];
        vl[idx] = s;
    }
    __syncthreads();

    const int jl = t & 63, kq = t >> 6;
    const int j  = blockIdx.x * 64 + jl;
    float acc = 0.f;
    #pragma unroll 8
    for (int k = kq * 128; k < kq * 128 + 128; ++k)
        acc = fmaf(vl[k], Wgc[k * N_HID1 + j], acc);

    sm[kq][jl] = acc;
    __syncthreads();
    if (t < 64)
        h0[blockIdx.x * 64 + t] = sm[0][t] + sm[1][t] + sm[2][t] + sm[3][t];
}

// ---------------- K3: h1[j] complete per block + fused finalize (last-arrive) ----------------
// 16 blocks x 32 j; thread (jl=t&31, kg=t>>5): 8 k-groups of 128 over full k<1024.
__global__ __launch_bounds__(256) void k3_h1_final(const float* __restrict__ h0,
                                                   const float* __restrict__ bgc,
                                                   const float* __restrict__ W1,
                                                   const float* __restrict__ b1,
                                                   const float* __restrict__ W2,
                                                   const float* __restrict__ b2,
                                                   const float* __restrict__ du0,
                                                   float* __restrict__ pd,
                                                   int* __restrict__ cnt,
                                                   float* __restrict__ out) {
    const int t = threadIdx.x;
    __shared__ float hl[N_HID1];
    __shared__ float sm[8][32];

    for (int idx = t; idx < N_HID1; idx += 256)
        hl[idx] = leaky(h0[idx] + bgc[idx]);
    __syncthreads();

    const int jl = t & 31, kg = t >> 5;
    const int j  = blockIdx.x * 32 + jl;
    float acc = 0.f;
    #pragma unroll 8
    for (int k = kg * 128; k < kg * 128 + 128; ++k)
        acc = fmaf(hl[k], W1[k * N_HID2 + j], acc);

    sm[kg][jl] = acc;
    __syncthreads();

    // lanes 0..31 (one half-wave) finish h1, apply bias/leaky/dropout, dot with W2
    if (t < 32) {
        float h1 = 0.f;
        #pragma unroll
        for (int g = 0; g < 8; ++g) h1 += sm[g][t];
        const int jj = blockIdx.x * 32 + t;
        float h = leaky(h1 + b1[jj]);
        h = (du0[jj] >= DROP_P) ? h / (1.0f - DROP_P) : 0.f;
        float term = h * W2[jj];
        #pragma unroll
        for (int off = 16; off; off >>= 1) term += __shfl_down(term, off, 32);
        if (t == 0) {
            pd[blockIdx.x] = term;
            __threadfence();  // release my pd store (device scope)
            int old = __hip_atomic_fetch_add(cnt, 1, __ATOMIC_ACQ_REL, __HIP_MEMORY_SCOPE_AGENT);
            if (old == K3_BLK - 1) {       // last block to finish: finalize
                __threadfence();           // acquire: see all pd stores
                float s = 0.f;
                #pragma unroll
                for (int b = 0; b < K3_BLK; ++b)
                    s += __hip_atomic_load(&pd[b], __ATOMIC_RELAXED, __HIP_MEMORY_SCOPE_AGENT);
                out[0] = s + b2[0];
            }
        }
    }
}

extern "C" void kernel_launch(void* const* d_in, const int* in_sizes, int n_in,
                              void* d_out, int out_size, void* d_ws, size_t ws_size,
                              hipStream_t stream) {
    const float* x   = (const float*)d_in[0];
    const float* adj = (const float*)d_in[1];  // row 0 = first 8192 floats
    const float* Wgc = (const float*)d_in[2];
    const float* bgc = (const float*)d_in[3];
    const float* W1  = (const float*)d_in[4];
    const float* b1  = (const float*)d_in[5];
    const float* W2  = (const float*)d_in[6];
    const float* b2  = (const float*)d_in[7];
    const float* du  = (const float*)d_in[8];  // row 0 = first 512 floats
    float* out = (float*)d_out;
    float* ws  = (float*)d_ws;

    float* vp  = ws + VP_OFF;
    float* h0  = ws + H0_OFF;
    float* pd  = ws + PD_OFF;
    int*   cnt = (int*)(ws + CNT_OFF);

    k1_adjrow_x<<<dim3(8, 32),  256, 0, stream>>>(x, adj, vp, cnt);
    k2_v_wgc   <<<dim3(K2_BLK), 256, 0, stream>>>(vp, Wgc, h0);
    k3_h1_final<<<dim3(K3_BLK), 256, 0, stream>>>(h0, bgc, W1, b1, W2, b2, du,
                                                  pd, cnt, out);
}

// Round 5
// 19.954 us; speedup vs baseline: 1.5219x; 1.2940x over previous
//
#include <hip/hip_runtime.h>

// GCNCountry: out = ((leaky(leaky(adj@(x@Wgc)+bgc) @ W1 + b1) * dropmask) @ W2 + b2)[0]
// -> depends ONLY on row 0 of every intermediate. Vector chain:
//    v  = adj[0,:] @ x            (16 MB x-read, K1, 256 blocks -> 32 partials)
//    h0 = v @ Wgc                 (2 MB, K2, 64 shallow blocks -> 16 partials)
//    h1 = leaky(h0+bgc) @ W1      (2 MB, K3, 32 shallow blocks -> 16 partials)
//    out = dropout(leaky(h1+b1)).W2 + b2   (last-arriving K3 block, fixed order)
//
// Regime lessons so far: node gap ~2.5-4us; spin grid-barrier ~10us (NEVER);
// last-arrive (no spinning) ~free; deep-k few-block kernels are latency-bound
// (~5-6us each) -- keep k-chunks <=64 loads/thread and >=32 blocks.

constexpr int N_FEAT  = 512;
constexpr int N_HID1  = 1024;
constexpr int N_HID2  = 512;
constexpr float SLOPE  = 0.01f;
constexpr float DROP_P = 0.3f;

constexpr int VP_N = 32;        // v partials  [32][512]
constexpr int H0_N = 16;        // h0 partials [16][1024]
constexpr int H1_N = 16;        // h1 partials [16][512]
constexpr int VP_OFF  = 0;
constexpr int H0_OFF  = 16384;
constexpr int H1_OFF  = 32768;
constexpr int CNT_OFF = 40960;  // 1 int, zeroed by K1 each call
constexpr int K3_BLKS = 32;

__device__ __forceinline__ float leaky(float x) { return x >= 0.f ? x : SLOPE * x; }

// ---------------- K1: v_part[rb][c] = sum_{rows in chunk rb} adj0[row] * x[row][c] ----------------
// grid (8 col-stripes of 64, 32 row-chunks of 256), 256 thr; float4 fully-coalesced x reads.
__global__ __launch_bounds__(256) void k1_adjrow_x(const float* __restrict__ x,
                                                   const float* __restrict__ adj0,
                                                   float* __restrict__ vp,
                                                   int* __restrict__ cnt) {
    const int tid = threadIdx.x;
    if (blockIdx.x == 0 && blockIdx.y == 0 && tid == 0) cnt[0] = 0;  // visible at kernel boundary

    const int f4  = tid & 15;
    const int r   = tid >> 4;          // 0..15
    const int c0  = blockIdx.x * 64;   // col stripe
    const int rb  = blockIdx.y;        // row chunk
    const float4* x4 = reinterpret_cast<const float4*>(x);

    float4 acc = {0.f, 0.f, 0.f, 0.f};
    int row = rb * 256 + r;
    #pragma unroll
    for (int it = 0; it < 16; ++it, row += 16) {
        const float  a  = adj0[row];
        const float4 xv = x4[row * (N_FEAT / 4) + (c0 >> 2) + f4];
        acc.x = fmaf(a, xv.x, acc.x);
        acc.y = fmaf(a, xv.y, acc.y);
        acc.z = fmaf(a, xv.z, acc.z);
        acc.w = fmaf(a, xv.w, acc.w);
    }

    __shared__ float4 sm[256];
    sm[tid] = acc;
    __syncthreads();
    #pragma unroll
    for (int off = 128; off >= 16; off >>= 1) {
        if (tid < off) {
            float4 o = sm[tid + off];
            sm[tid].x += o.x; sm[tid].y += o.y; sm[tid].z += o.z; sm[tid].w += o.w;
        }
        __syncthreads();
    }
    if (tid < 16)
        reinterpret_cast<float4*>(vp + rb * N_FEAT + c0)[tid] = sm[tid];
}

// ---------------- K2: h0_part[kc][j] = sum_{k in chunk kc} v[k] * Wgc[k][j] ----------------
// grid (4 j-blocks, 16 k-chunks of 32), 256 thr; one load-latency exposure per thread.
__global__ __launch_bounds__(256) void k2_v_wgc(const float* __restrict__ vp,
                                                const float* __restrict__ Wgc,
                                                float* __restrict__ h0p) {
    const int j  = blockIdx.x * 256 + threadIdx.x;   // 0..1023
    const int kc = blockIdx.y;
    const int k0 = kc * 32;

    __shared__ float vl[32];
    if (threadIdx.x < 32) {
        float s = 0.f;
        #pragma unroll
        for (int p = 0; p < VP_N; ++p) s += vp[p * N_FEAT + k0 + threadIdx.x];
        vl[threadIdx.x] = s;
    }
    __syncthreads();

    float acc = 0.f;
    #pragma unroll
    for (int k = 0; k < 32; ++k)
        acc = fmaf(vl[k], Wgc[(k0 + k) * N_HID1 + j], acc);
    h0p[kc * N_HID1 + j] = acc;
}

// ---------------- K3: h1 partials + fused finalize (last-arrive, no spinning) ----------------
// grid (2 j-blocks, 16 k-chunks of 64), 256 thr.
__global__ __launch_bounds__(256) void k3_h1_final(const float* __restrict__ h0p,
                                                   const float* __restrict__ bgc,
                                                   const float* __restrict__ W1,
                                                   const float* __restrict__ b1,
                                                   const float* __restrict__ W2,
                                                   const float* __restrict__ b2,
                                                   const float* __restrict__ du0,
                                                   float* __restrict__ h1p,
                                                   int* __restrict__ cnt,
                                                   float* __restrict__ out) {
    const int t  = threadIdx.x;
    const int j  = blockIdx.x * 256 + t;   // 0..511
    const int kc = blockIdx.y;
    const int k0 = kc * 64;

    __shared__ float hl[64];
    if (t < 64) {
        const int k = k0 + t;
        float s = bgc[k];
        #pragma unroll
        for (int p = 0; p < H0_N; ++p) s += h0p[p * N_HID1 + k];
        hl[t] = leaky(s);
    }
    __syncthreads();

    float acc = 0.f;
    #pragma unroll
    for (int k = 0; k < 64; ++k)
        acc = fmaf(hl[k], W1[(k0 + k) * N_HID2 + j], acc);
    h1p[kc * N_HID2 + j] = acc;

    // ---- last-arrive: the 32nd block to pass here finalizes alone ----
    __shared__ int amLast;
    __threadfence();          // each thread releases its own h1p store (device scope)
    __syncthreads();
    if (t == 0) {
        int old = __hip_atomic_fetch_add(cnt, 1, __ATOMIC_ACQ_REL, __HIP_MEMORY_SCOPE_AGENT);
        amLast = (old == K3_BLKS - 1);
    }
    __syncthreads();
    if (!amLast) return;
    __threadfence();          // acquire: see all other blocks' h1p stores

    float term = 0.f;
    #pragma unroll
    for (int rep = 0; rep < 2; ++rep) {
        const int jj = rep * 256 + t;
        float s = b1[jj];
        #pragma unroll
        for (int p = 0; p < H1_N; ++p) s += h1p[p * N_HID2 + jj];
        float h = leaky(s);
        h = (du0[jj] >= DROP_P) ? h / (1.0f - DROP_P) : 0.f;
        term = fmaf(h, W2[jj], term);
    }
    #pragma unroll
    for (int off = 32; off; off >>= 1) term += __shfl_down(term, off, 64);
    __shared__ float red[4];
    if ((t & 63) == 0) red[t >> 6] = term;
    __syncthreads();
    if (t == 0)
        out[0] = red[0] + red[1] + red[2] + red[3] + b2[0];
}

extern "C" void kernel_launch(void* const* d_in, const int* in_sizes, int n_in,
                              void* d_out, int out_size, void* d_ws, size_t ws_size,
                              hipStream_t stream) {
    const float* x   = (const float*)d_in[0];
    const float* adj = (const float*)d_in[1];  // row 0 = first 8192 floats
    const float* Wgc = (const float*)d_in[2];
    const float* bgc = (const float*)d_in[3];
    const float* W1  = (const float*)d_in[4];
    const float* b1  = (const float*)d_in[5];
    const float* W2  = (const float*)d_in[6];
    const float* b2  = (const float*)d_in[7];
    const float* du  = (const float*)d_in[8];  // row 0 = first 512 floats
    float* out = (float*)d_out;
    float* ws  = (float*)d_ws;

    float* vp  = ws + VP_OFF;
    float* h0p = ws + H0_OFF;
    float* h1p = ws + H1_OFF;
    int*   cnt = (int*)(ws + CNT_OFF);

    k1_adjrow_x<<<dim3(8, 32), 256, 0, stream>>>(x, adj, vp, cnt);
    k2_v_wgc  <<<dim3(4, 16), 256, 0, stream>>>(vp, Wgc, h0p);
    k3_h1_final<<<dim3(2, 16), 256, 0, stream>>>(h0p, bgc, W1, b1, W2, b2, du,
                                                 h1p, cnt, out);
}

// Round 6
// 16.610 us; speedup vs baseline: 1.8282x; 1.2013x over previous
//
#include <hip/hip_runtime.h>

// GCNCountry: out = ((leaky(leaky(adj@(x@Wgc)+bgc) @ W1 + b1) * dropmask) @ W2 + b2)[0]
// -> depends ONLY on row 0 of every intermediate. Vector chain:
//    v  = adj[0,:] @ x            (16 MB x-read, K1, 256 blocks -> 32 partials)
//    h0 = v @ Wgc; h1 = leaky(h0+bgc) @ W1; out = dropout(leaky(h1+b1)).W2+b2
//       -> ALL fused in K23 (32 blocks): each block redundantly computes its own
//          64-wide h0 chunk (2x read of L3-resident Wgc, ~free), h1 partial,
//          then t0-only RELEASE fetch_add; last-arriving block finalizes.
//
// Cost model from rounds 1-5: node gap ~3us; spin grid-barrier ~10us (never);
// per-thread agent fences ~5us across 32 blocks (round 5 mistake -- fence must
// be ONE thread per block, AFTER the block's work); deep-k loops must be fully
// unrolled float4 streams (one latency exposure), not 16 serialized batches.

constexpr int N_FEAT  = 512;
constexpr int N_HID1  = 1024;
constexpr int N_HID2  = 512;
constexpr float SLOPE  = 0.01f;
constexpr float DROP_P = 0.3f;

constexpr int VP_N   = 32;      // v partials [32][512]
constexpr int VP_OFF = 0;
constexpr int H1_OFF = 16384;   // h1 partials [16][512]
constexpr int CNT_OFF = 24576;  // 1 int, zeroed by K1 each call
constexpr int NBLK2  = 32;      // K23 grid

__device__ __forceinline__ float leaky(float x) { return x >= 0.f ? x : SLOPE * x; }

// ---------------- K1: v_part[rb][c] = sum_{rows in chunk rb} adj0[row] * x[row][c] ----------------
// grid (8 col-stripes of 64, 32 row-chunks of 256), 256 thr; float4 fully-coalesced x reads.
__global__ __launch_bounds__(256) void k1_adjrow_x(const float* __restrict__ x,
                                                   const float* __restrict__ adj0,
                                                   float* __restrict__ vp,
                                                   int* __restrict__ cnt) {
    const int tid = threadIdx.x;
    if (blockIdx.x == 0 && blockIdx.y == 0 && tid == 0) cnt[0] = 0;  // visible at kernel boundary

    const int f4  = tid & 15;
    const int r   = tid >> 4;          // 0..15
    const int c0  = blockIdx.x * 64;   // col stripe
    const int rb  = blockIdx.y;        // row chunk
    const float4* x4 = reinterpret_cast<const float4*>(x);

    float4 acc = {0.f, 0.f, 0.f, 0.f};
    int row = rb * 256 + r;
    #pragma unroll
    for (int it = 0; it < 16; ++it, row += 16) {
        const float  a  = adj0[row];
        const float4 xv = x4[row * (N_FEAT / 4) + (c0 >> 2) + f4];
        acc.x = fmaf(a, xv.x, acc.x);
        acc.y = fmaf(a, xv.y, acc.y);
        acc.z = fmaf(a, xv.z, acc.z);
        acc.w = fmaf(a, xv.w, acc.w);
    }

    __shared__ float4 sm[256];
    sm[tid] = acc;
    __syncthreads();
    #pragma unroll
    for (int off = 128; off >= 16; off >>= 1) {
        if (tid < off) {
            float4 o = sm[tid + off];
            sm[tid].x += o.x; sm[tid].y += o.y; sm[tid].z += o.z; sm[tid].w += o.w;
        }
        __syncthreads();
    }
    if (tid < 16)
        reinterpret_cast<float4*>(vp + rb * N_FEAT + c0)[tid] = sm[tid];
}

// ---------------- K23: redundant h0 chunk + h1 partial + last-arrive finalize ----------------
// 32 blocks = (jb = bid&1: j-half of 256) x (kc = bid>>1: k-chunk of 64).
__global__ __launch_bounds__(256, 1) void k23_fused(const float* __restrict__ vp,
                                                    const float* __restrict__ Wgc,
                                                    const float* __restrict__ bgc,
                                                    const float* __restrict__ W1,
                                                    const float* __restrict__ b1,
                                                    const float* __restrict__ W2,
                                                    const float* __restrict__ b2,
                                                    const float* __restrict__ du0,
                                                    float* __restrict__ h1p,
                                                    int* __restrict__ cnt,
                                                    float* __restrict__ out) {
    const int t  = threadIdx.x;
    const int jb = blockIdx.x & 1;
    const int kc = blockIdx.x >> 1;
    const int k0 = kc * 64;

    __shared__ float4 vl4[128];      // full v (512 floats)
    __shared__ float4 va[128];       // phase-A scratch
    __shared__ float  hl[64];        // leaky(h0+bgc) chunk
    __shared__ float  smb[16][65];   // phase-B partial reduce (padded)

    // ---- Phase A: v = sum of 32 partials (float4, 2 p-halves, one latency exposure) ----
    {
        const float4* vp4 = reinterpret_cast<const float4*>(vp);
        const int slot = t & 127;
        const int ph   = t >> 7;     // 0,1
        float4 a = {0.f, 0.f, 0.f, 0.f};
        #pragma unroll
        for (int p = 0; p < 16; ++p) {
            const float4 xv = vp4[(ph * 16 + p) * 128 + slot];
            a.x += xv.x; a.y += xv.y; a.z += xv.z; a.w += xv.w;
        }
        if (ph == 0) va[slot] = a;
        __syncthreads();
        if (ph == 1) {
            float4 o = va[slot];
            o.x += a.x; o.y += a.y; o.z += a.z; o.w += a.w;
            vl4[slot] = o;
        }
        __syncthreads();
    }

    // ---- Phase B: h0[k0..k0+64) = v @ Wgc[:, chunk]; 16 m-groups x 16 float4 k-slots ----
    {
        const float* vlf = reinterpret_cast<const float*>(vl4);
        const float4* Wgc4 = reinterpret_cast<const float4*>(Wgc);
        const int f4 = t & 15;       // k-slot (4 k each)
        const int mg = t >> 4;       // m-group of 32
        float4 acc = {0.f, 0.f, 0.f, 0.f};
        #pragma unroll
        for (int i = 0; i < 32; ++i) {
            const int m = mg * 32 + i;
            const float4 w = Wgc4[m * (N_HID1 / 4) + (k0 >> 2) + f4];
            const float vm = vlf[m];
            acc.x = fmaf(vm, w.x, acc.x);
            acc.y = fmaf(vm, w.y, acc.y);
            acc.z = fmaf(vm, w.z, acc.z);
            acc.w = fmaf(vm, w.w, acc.w);
        }
        smb[mg][f4 * 4 + 0] = acc.x;
        smb[mg][f4 * 4 + 1] = acc.y;
        smb[mg][f4 * 4 + 2] = acc.z;
        smb[mg][f4 * 4 + 3] = acc.w;
        __syncthreads();
        if (t < 64) {
            float s = bgc[k0 + t];
            #pragma unroll
            for (int g = 0; g < 16; ++g) s += smb[g][t];
            hl[t] = leaky(s);
        }
        __syncthreads();
    }

    // ---- Phase C: h1 partial for (jb, kc) ----
    {
        const int j = jb * 256 + t;  // 0..511
        float acc = 0.f;
        #pragma unroll
        for (int k = 0; k < 64; ++k)
            acc = fmaf(hl[k], W1[(k0 + k) * N_HID2 + j], acc);
        h1p[kc * N_HID2 + j] = acc;
    }

    // ---- last-arrive: t0-only release; only the 32nd block pays an acquire ----
    __shared__ int amLast;
    __syncthreads();   // drains h1p stores to L2 (vmcnt(0) before s_barrier)
    if (t == 0) {
        // RELEASE: s_waitcnt + buffer_wbl2 -> whole-L2 writeback covers the
        // block's already-drained h1p stores; no invalidate on this path.
        int old = __hip_atomic_fetch_add(cnt, 1, __ATOMIC_RELEASE, __HIP_MEMORY_SCOPE_AGENT);
        amLast = (old == NBLK2 - 1);
    }
    __syncthreads();
    if (!amLast) return;
    if (t == 0)  // ACQUIRE: invalidate this CU's L1 + XCD L2 once, then read fresh
        (void)__hip_atomic_load(cnt, __ATOMIC_ACQUIRE, __HIP_MEMORY_SCOPE_AGENT);
    __syncthreads();

    // ---- Phase D: reduce h1 partials, bias+leaky+dropout, dot W2[:,0], +b2 ----
    {
        float term = 0.f;
        #pragma unroll
        for (int rep = 0; rep < 2; ++rep) {
            const int jj = rep * 256 + t;
            float s = b1[jj];
            #pragma unroll
            for (int p = 0; p < 16; ++p) s += h1p[p * N_HID2 + jj];
            float h = leaky(s);
            h = (du0[jj] >= DROP_P) ? h / (1.0f - DROP_P) : 0.f;
            term = fmaf(h, W2[jj], term);
        }
        #pragma unroll
        for (int off = 32; off; off >>= 1) term += __shfl_down(term, off, 64);
        __shared__ float red[4];
        if ((t & 63) == 0) red[t >> 6] = term;
        __syncthreads();
        if (t == 0)
            out[0] = red[0] + red[1] + red[2] + red[3] + b2[0];
    }
}

extern "C" void kernel_launch(void* const* d_in, const int* in_sizes, int n_in,
                              void* d_out, int out_size, void* d_ws, size_t ws_size,
                              hipStream_t stream) {
    const float* x   = (const float*)d_in[0];
    const float* adj = (const float*)d_in[1];  // row 0 = first 8192 floats
    const float* Wgc = (const float*)d_in[2];
    const float* bgc = (const float*)d_in[3];
    const float* W1  = (const float*)d_in[4];
    const float* b1  = (const float*)d_in[5];
    const float* W2  = (const float*)d_in[6];
    const float* b2  = (const float*)d_in[7];
    const float* du  = (const float*)d_in[8];  // row 0 = first 512 floats
    float* out = (float*)d_out;
    float* ws  = (float*)d_ws;

    float* vp  = ws + VP_OFF;
    float* h1p = ws + H1_OFF;
    int*   cnt = (int*)(ws + CNT_OFF);

    k1_adjrow_x<<<dim3(8, 32),   256, 0, stream>>>(x, adj, vp, cnt);
    k23_fused  <<<dim3(NBLK2),   256, 0, stream>>>(vp, Wgc, bgc, W1, b1, W2, b2, du,
                                                   h1p, cnt, out);
}